// Round 6
// baseline (1020.706 us; speedup 1.0000x reference)
//
#include <hip/hip_runtime.h>
#include <math.h>

#define N_ 4096
#define V_ 4
#define C_ 256

typedef __attribute__((ext_vector_type(8))) short bf16x8;
typedef __attribute__((ext_vector_type(4))) float f32x4;

// ---------------- workspace byte offsets ----------------
#define OFF_DN     0ull
#define OFF_R      16777216ull
#define OFF_DNHI   33554432ull
#define OFF_DNLO   41943040ull
#define OFF_SFT    50331648ull
#define OFF_E      58720256ull
#define OFF_ACC    92274688ull      // 8 slices (dir*4+ks) x 4096x256 f32 = 32MB
#define OFF_RPMAX  125829120ull
#define OFF_RPARG  126877696ull
#define OFF_RPSUM  127926272ull
#define OFF_CPMAX  128974848ull
#define OFF_CPARG  130023424ull
#define OFF_CPSUM  131072000ull
#define OFF_RARG   132120576ull
#define OFF_RSUM   132136960ull
#define OFF_CARG   132153344ull
#define OFF_CSUM   132169728ull
#define OFF_RELWT  132186112ull
#define OFF_SQ     132202496ull
#define OFF_CNT    132202560ull

__device__ __forceinline__ unsigned short f2bf(float x) {
    unsigned int u = __float_as_uint(x);
    u += 0x7fffu + ((u >> 16) & 1u);
    return (unsigned short)(u >> 16);
}
__device__ __forceinline__ float bf2f(unsigned short h) {
    return __uint_as_float(((unsigned int)h) << 16);
}
__device__ __forceinline__ f32x4 mfma16(bf16x8 a, bf16x8 b, f32x4 c) {
    return __builtin_amdgcn_mfma_f32_16x16x32_bf16(a, b, c, 0, 0, 0);
}

// ---- normalize + bf16 hi/lo split: dn[v][n][c] ----
__global__ void normalize_k(const float* __restrict__ desc, float* __restrict__ dn,
                            unsigned short* __restrict__ dnh, unsigned short* __restrict__ dnl) {
    int row = blockIdx.x;            // n*V + v
    int n = row >> 2, v = row & 3;
    int c = threadIdx.x;
    float x = desc[(size_t)row * C_ + c];
    __shared__ float red[256];
    red[c] = x * x;
    __syncthreads();
    for (int s = 128; s > 0; s >>= 1) {
        if (c < s) red[c] += red[c + s];
        __syncthreads();
    }
    float inv = 1.0f / fmaxf(sqrtf(red[0]), 1e-12f);
    float y = x * inv;
    size_t o = ((size_t)v * N_ + n) * C_ + c;
    dn[o] = y;
    unsigned short h = f2bf(y);
    dnh[o] = h;
    dnl[o] = f2bf(y - bf2f(h));
}

// ---- R_v = dn_v @ W_rec ----
__global__ void rmatmul_k(const float* __restrict__ dn, const float* __restrict__ Wrec,
                          float* __restrict__ R) {
    int v = blockIdx.y;
    int m0 = blockIdx.x * 16;
    __shared__ float rows[16][C_];
    const float* base = dn + ((size_t)v * N_ + m0) * C_;
    for (int r = 0; r < 16; ++r) rows[r][threadIdx.x] = base[(size_t)r * C_ + threadIdx.x];
    __syncthreads();
    float acc[16];
#pragma unroll
    for (int r = 0; r < 16; ++r) acc[r] = 0.f;
    int c = threadIdx.x;
    for (int k = 0; k < C_; ++k) {
        float w = Wrec[(size_t)k * C_ + c];
#pragma unroll
        for (int r = 0; r < 16; ++r) acc[r] += rows[r][k] * w;
    }
    float* outp = R + ((size_t)v * N_ + m0) * C_ + c;
    for (int r = 0; r < 16; ++r) outp[(size_t)r * C_] = acc[r];
}

// ---- relWT[p][c], p = i*4+j ----
__global__ void relwt_k(const float* __restrict__ T, const float* __restrict__ WT,
                        float* __restrict__ relwt) {
    int p = blockIdx.x; int i = p >> 2, j = p & 3;
    if (i == j) return;
    int c = threadIdx.x;
    float acc = 0.f;
    for (int k = 0; k < 16; ++k) acc += T[i * 16 + k] * WT[(size_t)k * C_ + c];
    for (int k = 0; k < 16; ++k) acc += T[j * 16 + k] * WT[(size_t)(16 + k) * C_ + c];
    relwt[(size_t)p * C_ + c] = acc;
}

// ---- sfT[v][c][n] = bf16(sf[n][v][c]) ----
__global__ void sfT_k(const float* __restrict__ sf, unsigned short* __restrict__ sfT) {
    __shared__ unsigned short Tt[64 * 72];   // [c][n], pitch 72
    int n0 = blockIdx.x * 64, c0 = blockIdx.y * 64, v = blockIdx.z;
    int t = threadIdx.x;
    int nr = t >> 2, cq = (t & 3) * 16;
    const float* src = sf + ((size_t)(n0 + nr) * V_ + v) * C_ + c0 + cq;
    for (int u = 0; u < 16; ++u) Tt[(cq + u) * 72 + nr] = f2bf(src[u]);
    __syncthreads();
    int cr = t >> 2, nq = (t & 3) * 16;
    unsigned short tmp[16] __attribute__((aligned(16)));
    for (int u = 0; u < 16; ++u) tmp[u] = Tt[cr * 72 + nq + u];
    unsigned short* dst = sfT + ((size_t)v * C_ + c0 + cr) * N_ + n0 + nq;
    *(uint4*)dst = *(const uint4*)tmp;
    *(uint4*)(dst + 8) = *(const uint4*)(tmp + 8);
}

__global__ void zero_k(float* sq, int* cnt) {
    if (threadIdx.x < 16) { sq[threadIdx.x] = 0.f; cnt[threadIdx.x] = 0; }
}

// ---- sim GEMM (split-bf16, 3 MFMA) + exp-once stats/E epilogue ----
__global__ __launch_bounds__(256) void sim_mfma_k(
    const unsigned short* __restrict__ Ahi, const unsigned short* __restrict__ Alo,
    const unsigned short* __restrict__ Bhi, const unsigned short* __restrict__ Blo,
    unsigned short* __restrict__ E,
    float* __restrict__ rpMax, int* __restrict__ rpArg, float* __restrict__ rpSum,
    float* __restrict__ cpMax, int* __restrict__ cpArg, float* __restrict__ cpSum) {
    __shared__ unsigned char smem[36864];
    __shared__ float sRedM[256];
    __shared__ int   sRedA[256];
    __shared__ float sRedS[256];
    unsigned short* sAh = (unsigned short*)smem;          // [64][72]
    unsigned short* sAl = sAh + 64 * 72;
    unsigned short* sBh = sAl + 64 * 72;
    unsigned short* sBl = sBh + 64 * 72;
    float* S = (float*)smem;                               // [64][65] (epilogue alias, holds expS)

    int tid = threadIdx.x;
    int m0 = blockIdx.y * 64, n0 = blockIdx.x * 64;
    int w = tid >> 6, l = tid & 63;
    int wm = w & 1, wn = w >> 1;
    int mr = l & 15, q = l >> 4;

    f32x4 acc[2][2];
#pragma unroll
    for (int a = 0; a < 2; ++a)
#pragma unroll
        for (int b = 0; b < 2; ++b)
#pragma unroll
            for (int u = 0; u < 4; ++u) acc[a][b][u] = 0.f;

    int r = tid >> 2;
    int k8 = (tid & 3) * 8;

    for (int k0 = 0; k0 < C_; k0 += 64) {
        size_t ga = (size_t)(m0 + r) * C_ + k0 + k8;
        size_t gb = (size_t)(n0 + r) * C_ + k0 + k8;
        uint4 a0 = *(const uint4*)(Ahi + ga);
        uint4 a1 = *(const uint4*)(Ahi + ga + 32);
        uint4 a2 = *(const uint4*)(Alo + ga);
        uint4 a3 = *(const uint4*)(Alo + ga + 32);
        uint4 b0 = *(const uint4*)(Bhi + gb);
        uint4 b1 = *(const uint4*)(Bhi + gb + 32);
        uint4 b2 = *(const uint4*)(Blo + gb);
        uint4 b3 = *(const uint4*)(Blo + gb + 32);
        *(uint4*)(sAh + r * 72 + k8)      = a0;
        *(uint4*)(sAh + r * 72 + k8 + 32) = a1;
        *(uint4*)(sAl + r * 72 + k8)      = a2;
        *(uint4*)(sAl + r * 72 + k8 + 32) = a3;
        *(uint4*)(sBh + r * 72 + k8)      = b0;
        *(uint4*)(sBh + r * 72 + k8 + 32) = b1;
        *(uint4*)(sBl + r * 72 + k8)      = b2;
        *(uint4*)(sBl + r * 72 + k8 + 32) = b3;
        __syncthreads();
#pragma unroll
        for (int ks = 0; ks < 64; ks += 32) {
            bf16x8 ah[2], al[2], bh[2], bl[2];
#pragma unroll
            for (int ti = 0; ti < 2; ++ti) {
                int mrow = wm * 32 + ti * 16 + mr;
                ah[ti] = *(const bf16x8*)(sAh + mrow * 72 + ks + q * 8);
                al[ti] = *(const bf16x8*)(sAl + mrow * 72 + ks + q * 8);
            }
#pragma unroll
            for (int tj = 0; tj < 2; ++tj) {
                int nrow = wn * 32 + tj * 16 + mr;
                bh[tj] = *(const bf16x8*)(sBh + nrow * 72 + ks + q * 8);
                bl[tj] = *(const bf16x8*)(sBl + nrow * 72 + ks + q * 8);
            }
#pragma unroll
            for (int ti = 0; ti < 2; ++ti)
#pragma unroll
                for (int tj = 0; tj < 2; ++tj) {
                    acc[ti][tj] = mfma16(ah[ti], bh[tj], acc[ti][tj]);
                    acc[ti][tj] = mfma16(ah[ti], bl[tj], acc[ti][tj]);
                    acc[ti][tj] = mfma16(al[ti], bh[tj], acc[ti][tj]);
                }
        }
        __syncthreads();
    }

    // ---- epilogue: dump expS tile to LDS (exp once; monotone -> same argmax) ----
#pragma unroll
    for (int ti = 0; ti < 2; ++ti)
#pragma unroll
        for (int tj = 0; tj < 2; ++tj)
#pragma unroll
            for (int rg = 0; rg < 4; ++rg)
                S[(wm * 32 + ti * 16 + q * 4 + rg) * 65 + wn * 32 + tj * 16 + mr] =
                    __expf(acc[ti][tj][rg]);
    __syncthreads();

    // row stats
    {
        int rr = tid >> 2, q4 = tid & 3;
        float mx = -1e30f; int ag = 0; float sm = 0.f;
        for (int cc = 0; cc < 16; ++cc) {
            int c = q4 * 16 + cc;
            float v = S[rr * 65 + c];
            sm += v;
            if (v > mx) { mx = v; ag = c; }
        }
        sRedM[tid] = mx; sRedA[tid] = ag; sRedS[tid] = sm;
    }
    __syncthreads();
    if (tid < 64) {
        float mx = -1e30f; int ag = 0; float sm = 0.f;
        for (int qq = 0; qq < 4; ++qq) {
            float v = sRedM[tid * 4 + qq];
            if (v > mx) { mx = v; ag = sRedA[tid * 4 + qq]; }
            sm += sRedS[tid * 4 + qq];
        }
        size_t o = (size_t)blockIdx.x * N_ + m0 + tid;
        rpMax[o] = mx; rpArg[o] = n0 + ag; rpSum[o] = sm;
    }
    __syncthreads();
    // col stats
    {
        int cc = tid >> 2, q4 = tid & 3;
        float mx = -1e30f; int ag = 0; float sm = 0.f;
        for (int rr = 0; rr < 16; ++rr) {
            int rrr = q4 * 16 + rr;
            float v = S[rrr * 65 + cc];
            sm += v;
            if (v > mx) { mx = v; ag = rrr; }
        }
        sRedM[tid] = mx; sRedA[tid] = ag; sRedS[tid] = sm;
    }
    __syncthreads();
    if (tid < 64) {
        float mx = -1e30f; int ag = 0; float sm = 0.f;
        for (int qq = 0; qq < 4; ++qq) {
            float v = sRedM[tid * 4 + qq];
            if (v > mx) { mx = v; ag = sRedA[tid * 4 + qq]; }
            sm += sRedS[tid * 4 + qq];
        }
        size_t o = (size_t)blockIdx.y * N_ + n0 + tid;
        cpMax[o] = mx; cpArg[o] = m0 + ag; cpSum[o] = sm;
    }
    // E store (bf16 of expS), row-major
    {
        int r2 = tid >> 2, cq = (tid & 3) * 16;
        unsigned short tmp[16] __attribute__((aligned(16)));
        for (int u = 0; u < 16; ++u) tmp[u] = f2bf(S[r2 * 65 + cq + u]);
        unsigned short* dst = E + (size_t)(m0 + r2) * N_ + n0 + cq;
        *(uint4*)dst = *(const uint4*)tmp;
        *(uint4*)(dst + 8) = *(const uint4*)(tmp + 8);
    }
}

// ---- fused merge of row/col tile-partials; grid (64, 2), 4 t-groups/block ----
__global__ __launch_bounds__(256) void merge_k(
    const float* __restrict__ rpMax, const int* __restrict__ rpArg,
    const float* __restrict__ rpSum, const float* __restrict__ cpMax,
    const int* __restrict__ cpArg, const float* __restrict__ cpSum,
    int* __restrict__ rowArg, float* __restrict__ rowSum,
    int* __restrict__ colArg, float* __restrict__ colSum) {
    int d = blockIdx.y;
    const float* pMax = d ? cpMax : rpMax;
    const int*   pArg = d ? cpArg : rpArg;
    const float* pSum = d ? cpSum : rpSum;
    int*   outArg = d ? colArg : rowArg;
    float* outSum = d ? colSum : rowSum;
    int tid = threadIdx.x;
    int li = tid & 63, g = tid >> 6;
    int m = blockIdx.x * 64 + li;
    float mx = -1e30f; int ag = 0; float sm = 0.f;
    for (int t = g * 16; t < g * 16 + 16; ++t) {
        float v = pMax[(size_t)t * N_ + m];
        if (v > mx) { mx = v; ag = pArg[(size_t)t * N_ + m]; }
        sm += pSum[(size_t)t * N_ + m];
    }
    __shared__ float sMx[256], sSm[256];
    __shared__ int sAg[256];
    sMx[g * 64 + li] = mx; sAg[g * 64 + li] = ag; sSm[g * 64 + li] = sm;
    __syncthreads();
    if (tid < 64) {
        float M = sMx[tid]; int A = sAg[tid]; float Ssum = sSm[tid];
        for (int gg = 1; gg < 4; ++gg) {
            float v = sMx[gg * 64 + tid];
            if (v > M) { M = v; A = sAg[gg * 64 + tid]; }
            Ssum += sSm[gg * 64 + tid];
        }
        outArg[m] = A; outSum[m] = Ssum;
    }
}

// ---- pass2: full-C tile (64m x 256c), split-K=4, both dirs ----
// grid: (64 m-tiles, 4 ks, 2 dir). E read once per (dir,ks) stripe.
__global__ __launch_bounds__(256) void p2_k(
    const unsigned short* __restrict__ E, const unsigned short* __restrict__ sfT,
    int iview, int jview, float* __restrict__ accb) {
    __shared__ unsigned short sA[64 * 66];    // dir0: [m][k]; dir1: [k][m]
    __shared__ unsigned short sB[256 * 66];   // [c][k]
    int tid = threadIdx.x;
    int m0 = blockIdx.x * 64;
    int ks = blockIdx.y, d = blockIdx.z;
    const unsigned short* B = sfT + (size_t)(d ? iview : jview) * C_ * N_;
    int kbase = ks * 1024, kend = kbase + 1024;
    int w = tid >> 6, l = tid & 63, wm = w & 1, wn = w >> 1;
    int mr = l & 15, q = l >> 4;
    f32x4 acc[2][8];
#pragma unroll
    for (int a = 0; a < 2; ++a)
#pragma unroll
        for (int b = 0; b < 8; ++b)
#pragma unroll
            for (int u = 0; u < 4; ++u) acc[a][b][u] = 0.f;
    int r = tid >> 2, k8 = (tid & 3) * 8;

    uint4 pa0, pa1, pb[4][2];
    {
        int k0 = kbase;
        if (d == 0) {
            pa0 = *(const uint4*)(E + (size_t)(m0 + r) * N_ + k0 + k8);
            pa1 = *(const uint4*)(E + (size_t)(m0 + r) * N_ + k0 + k8 + 32);
        } else {
            pa0 = *(const uint4*)(E + (size_t)(k0 + r) * N_ + m0 + k8);
            pa1 = *(const uint4*)(E + (size_t)(k0 + r) * N_ + m0 + k8 + 32);
        }
#pragma unroll
        for (int ch = 0; ch < 4; ++ch) {
            pb[ch][0] = *(const uint4*)(B + (size_t)(ch * 64 + r) * N_ + k0 + k8);
            pb[ch][1] = *(const uint4*)(B + (size_t)(ch * 64 + r) * N_ + k0 + k8 + 32);
        }
    }

    for (int k0 = kbase; k0 < kend; k0 += 64) {
        *(uint4*)(sA + r * 66 + k8)      = pa0;
        *(uint4*)(sA + r * 66 + k8 + 32) = pa1;
#pragma unroll
        for (int ch = 0; ch < 4; ++ch) {
            *(uint4*)(sB + (ch * 64 + r) * 66 + k8)      = pb[ch][0];
            *(uint4*)(sB + (ch * 64 + r) * 66 + k8 + 32) = pb[ch][1];
        }
        __syncthreads();
        int kn = k0 + 64;
        if (kn < kend) {
            if (d == 0) {
                pa0 = *(const uint4*)(E + (size_t)(m0 + r) * N_ + kn + k8);
                pa1 = *(const uint4*)(E + (size_t)(m0 + r) * N_ + kn + k8 + 32);
            } else {
                pa0 = *(const uint4*)(E + (size_t)(kn + r) * N_ + m0 + k8);
                pa1 = *(const uint4*)(E + (size_t)(kn + r) * N_ + m0 + k8 + 32);
            }
#pragma unroll
            for (int ch = 0; ch < 4; ++ch) {
                pb[ch][0] = *(const uint4*)(B + (size_t)(ch * 64 + r) * N_ + kn + k8);
                pb[ch][1] = *(const uint4*)(B + (size_t)(ch * 64 + r) * N_ + kn + k8 + 32);
            }
        }
#pragma unroll
        for (int ksub = 0; ksub < 64; ksub += 32) {
            bf16x8 af[2], bfr[8];
            if (d == 0) {
#pragma unroll
                for (int ti = 0; ti < 2; ++ti)
                    af[ti] = *(const bf16x8*)(sA + (wm * 32 + ti * 16 + mr) * 66 + ksub + q * 8);
            } else {
#pragma unroll
                for (int ti = 0; ti < 2; ++ti) {
                    bf16x8 t;
#pragma unroll
                    for (int u = 0; u < 8; ++u)
                        t[u] = (short)sA[(ksub + q * 8 + u) * 66 + wm * 32 + ti * 16 + mr];
                    af[ti] = t;
                }
            }
#pragma unroll
            for (int tj = 0; tj < 8; ++tj)
                bfr[tj] = *(const bf16x8*)(sB + (wn * 128 + tj * 16 + mr) * 66 + ksub + q * 8);
#pragma unroll
            for (int ti = 0; ti < 2; ++ti)
#pragma unroll
                for (int tj = 0; tj < 8; ++tj)
                    acc[ti][tj] = mfma16(af[ti], bfr[tj], acc[ti][tj]);
        }
        __syncthreads();
    }
    float* accs = accb + (size_t)(d * 4 + ks) * N_ * C_;
#pragma unroll
    for (int ti = 0; ti < 2; ++ti)
#pragma unroll
        for (int tj = 0; tj < 8; ++tj) {
            int c = wn * 128 + tj * 16 + mr;
#pragma unroll
            for (int rg = 0; rg < 4; ++rg) {
                int m = m0 + wm * 32 + ti * 16 + q * 4 + rg;
                accs[(size_t)m * C_ + c] = acc[ti][tj][rg];
            }
        }
}

// ---- combine: 4 split-K slices -> softmax, mask, loss + count; grid (128, 2) ----
__global__ __launch_bounds__(256) void combine_k(
    const float* __restrict__ accb, const int* __restrict__ rowArg,
    const int* __restrict__ colArg, const float* __restrict__ rowSum,
    const float* __restrict__ colSum, const float* __restrict__ Ri,
    const float* __restrict__ Rj, const float* __restrict__ relwt,
    int pid0, int pid1, float* __restrict__ pairSq, int* __restrict__ pairCnt) {
    int d = blockIdx.y;
    const size_t NC = (size_t)N_ * C_;
    const float* s0 = accb + (size_t)(d * 4) * NC;
    const int* fa = d ? colArg : rowArg;
    const int* ba = d ? rowArg : colArg;
    const float* sum = d ? colSum : rowSum;
    const float* Rr = d ? Rj : Ri;
    int pid = d ? pid1 : pid0;
    const float* rw = relwt + (size_t)pid * C_;
    int y0 = blockIdx.x * 32;
    __shared__ float invS[32];
    __shared__ int mutS[32];
    int tid = threadIdx.x;
    if (tid < 32) {
        int y = y0 + tid;
        mutS[tid] = (ba[fa[y]] == y) ? 1 : 0;
        invS[tid] = 1.0f / sum[y];
    }
    __syncthreads();
    int c = tid;
    float rwc = rw[c];
    float local = 0.f;
    for (int rr = 0; rr < 32; ++rr) {
        if (mutS[rr]) {
            size_t o = (size_t)(y0 + rr) * C_ + c;
            float soft = (s0[o] + s0[o + NC] + s0[o + 2 * NC] + s0[o + 3 * NC]) * invS[rr];
            float dv = Rr[o] + rwc - soft;
            local += dv * dv;
        }
    }
    __shared__ float red[256];
    red[tid] = local;
    __syncthreads();
    for (int s = 128; s > 0; s >>= 1) {
        if (tid < s) red[tid] += red[tid + s];
        __syncthreads();
    }
    if (tid == 0) {
        atomicAdd(pairSq + pid, red[0]);
        int cnt = 0;
        for (int u = 0; u < 32; ++u) cnt += mutS[u];
        atomicAdd(pairCnt + pid, cnt);
    }
}

// ---- final scalar combine ----
__global__ void final_k(const float* __restrict__ sq, const int* __restrict__ cnt,
                        float* __restrict__ out) {
    if (threadIdx.x == 0 && blockIdx.x == 0) {
        float loss = 0.f, count = 0.f;
        for (int p = 0; p < 16; ++p) {
            int i = p >> 2, j = p & 3;
            if (i == j) continue;
            float ns = (float)cnt[p];
            if (ns > 0.f) { loss += sq[p] / fmaxf(ns * (float)C_, 1.0f); count += 1.f; }
        }
        out[0] = (count > 0.f) ? loss / count : 0.f;
    }
}

extern "C" void kernel_launch(void* const* d_in, const int* in_sizes, int n_in,
                              void* d_out, int out_size, void* d_ws, size_t ws_size,
                              hipStream_t stream) {
    const float* desc = (const float*)d_in[0];
    const float* sf   = (const float*)d_in[1];
    const float* T    = (const float*)d_in[2];
    const float* Wrec = (const float*)d_in[3];
    const float* WT   = (const float*)d_in[4];
    float* out = (float*)d_out;
    char* ws = (char*)d_ws;

    float*          dn    = (float*)(ws + OFF_DN);
    float*          R     = (float*)(ws + OFF_R);
    unsigned short* dnh   = (unsigned short*)(ws + OFF_DNHI);
    unsigned short* dnl   = (unsigned short*)(ws + OFF_DNLO);
    unsigned short* sfT   = (unsigned short*)(ws + OFF_SFT);
    unsigned short* E     = (unsigned short*)(ws + OFF_E);
    float* accb  = (float*)(ws + OFF_ACC);
    float* rpMax = (float*)(ws + OFF_RPMAX);
    int*   rpArg = (int*)(ws + OFF_RPARG);
    float* rpSum = (float*)(ws + OFF_RPSUM);
    float* cpMax = (float*)(ws + OFF_CPMAX);
    int*   cpArg = (int*)(ws + OFF_CPARG);
    float* cpSum = (float*)(ws + OFF_CPSUM);
    int*   rowArg = (int*)(ws + OFF_RARG);
    float* rowSum = (float*)(ws + OFF_RSUM);
    int*   colArg = (int*)(ws + OFF_CARG);
    float* colSum = (float*)(ws + OFF_CSUM);
    float* relwt = (float*)(ws + OFF_RELWT);
    float* pairSq = (float*)(ws + OFF_SQ);
    int*   pairCnt = (int*)(ws + OFF_CNT);

    normalize_k<<<N_ * V_, 256, 0, stream>>>(desc, dn, dnh, dnl);
    rmatmul_k<<<dim3(N_ / 16, V_), 256, 0, stream>>>(dn, Wrec, R);
    sfT_k<<<dim3(64, 4, 4), 256, 0, stream>>>(sf, sfT);
    relwt_k<<<16, 256, 0, stream>>>(T, WT, relwt);
    zero_k<<<1, 64, 0, stream>>>(pairSq, pairCnt);

    for (int i = 0; i < V_; ++i) {
        for (int j = i + 1; j < V_; ++j) {
            const unsigned short* Ahi = dnh + (size_t)i * N_ * C_;
            const unsigned short* Alo = dnl + (size_t)i * N_ * C_;
            const unsigned short* Bhi = dnh + (size_t)j * N_ * C_;
            const unsigned short* Blo = dnl + (size_t)j * N_ * C_;
            sim_mfma_k<<<dim3(64, 64), 256, 0, stream>>>(
                Ahi, Alo, Bhi, Blo, E, rpMax, rpArg, rpSum, cpMax, cpArg, cpSum);
            merge_k<<<dim3(64, 2), 256, 0, stream>>>(
                rpMax, rpArg, rpSum, cpMax, cpArg, cpSum, rowArg, rowSum, colArg, colSum);
            int pid0 = i * 4 + j, pid1 = j * 4 + i;
            p2_k<<<dim3(64, 4, 2), 256, 0, stream>>>(E, sfT, i, j, accb);
            combine_k<<<dim3(128, 2), 256, 0, stream>>>(
                accb, rowArg, colArg, rowSum, colSum,
                R + (size_t)i * N_ * C_, R + (size_t)j * N_ * C_,
                relwt, pid0, pid1, pairSq, pairCnt);
        }
    }
    final_k<<<1, 64, 0, stream>>>(pairSq, pairCnt, out);
}

// Round 7
// 688.179 us; speedup vs baseline: 1.4832x; 1.4832x over previous
//
#include <hip/hip_runtime.h>
#include <math.h>

#define N_ 4096
#define V_ 4
#define C_ 256

typedef __attribute__((ext_vector_type(8))) short bf16x8;
typedef __attribute__((ext_vector_type(4))) float f32x4;

// ---------------- workspace byte offsets ----------------
#define OFF_DN     0ull           // f32 4096x256x4v   16MB
#define OFF_R      16777216ull    // f32               16MB
#define OFF_DNHI   33554432ull    // bf16               8MB
#define OFF_DNLO   41943040ull    // bf16               8MB
#define OFF_SFT    50331648ull    // fp8 sfT[v][c][n]   4MB
#define OFF_E      54525952ull    // fp8 E[m][n]       16MB
#define OFF_ET     71303168ull    // fp8 ET[n][m]      16MB
#define OFF_RPMAX  88080384ull
#define OFF_RPARG  89128960ull
#define OFF_RPSUM  90177536ull
#define OFF_CPMAX  91226112ull
#define OFF_CPARG  92274688ull
#define OFF_CPSUM  93323264ull
#define OFF_RARG   94371840ull
#define OFF_RSUM   94388224ull
#define OFF_CARG   94404608ull
#define OFF_CSUM   94420992ull
#define OFF_RELWT  94437376ull
#define OFF_SQ     94453760ull
#define OFF_CNT    94453824ull

__device__ __forceinline__ unsigned short f2bf(float x) {
    unsigned int u = __float_as_uint(x);
    u += 0x7fffu + ((u >> 16) & 1u);
    return (unsigned short)(u >> 16);
}
__device__ __forceinline__ float bf2f(unsigned short h) {
    return __uint_as_float(((unsigned int)h) << 16);
}
__device__ __forceinline__ f32x4 mfma16(bf16x8 a, bf16x8 b, f32x4 c) {
    return __builtin_amdgcn_mfma_f32_16x16x32_bf16(a, b, c, 0, 0, 0);
}
// pack 4 f32 -> 4 fp8-e4m3 bytes (HW RNE conversion; OCP format on gfx950)
__device__ __forceinline__ unsigned int pk4fp8(float x0, float x1, float x2, float x3) {
    int w = 0;
    w = __builtin_amdgcn_cvt_pk_fp8_f32(x0, x1, w, false);
    w = __builtin_amdgcn_cvt_pk_fp8_f32(x2, x3, w, true);
    return (unsigned int)w;
}

// ---- normalize + bf16 hi/lo split: dn[v][n][c] ----
__global__ void normalize_k(const float* __restrict__ desc, float* __restrict__ dn,
                            unsigned short* __restrict__ dnh, unsigned short* __restrict__ dnl) {
    int row = blockIdx.x;            // n*V + v
    int n = row >> 2, v = row & 3;
    int c = threadIdx.x;
    float x = desc[(size_t)row * C_ + c];
    __shared__ float red[256];
    red[c] = x * x;
    __syncthreads();
    for (int s = 128; s > 0; s >>= 1) {
        if (c < s) red[c] += red[c + s];
        __syncthreads();
    }
    float inv = 1.0f / fmaxf(sqrtf(red[0]), 1e-12f);
    float y = x * inv;
    size_t o = ((size_t)v * N_ + n) * C_ + c;
    dn[o] = y;
    unsigned short h = f2bf(y);
    dnh[o] = h;
    dnl[o] = f2bf(y - bf2f(h));
}

// ---- R_v = dn_v @ W_rec ----
__global__ void rmatmul_k(const float* __restrict__ dn, const float* __restrict__ Wrec,
                          float* __restrict__ R) {
    int v = blockIdx.y;
    int m0 = blockIdx.x * 16;
    __shared__ float rows[16][C_];
    const float* base = dn + ((size_t)v * N_ + m0) * C_;
    for (int r = 0; r < 16; ++r) rows[r][threadIdx.x] = base[(size_t)r * C_ + threadIdx.x];
    __syncthreads();
    float acc[16];
#pragma unroll
    for (int r = 0; r < 16; ++r) acc[r] = 0.f;
    int c = threadIdx.x;
    for (int k = 0; k < C_; ++k) {
        float w = Wrec[(size_t)k * C_ + c];
#pragma unroll
        for (int r = 0; r < 16; ++r) acc[r] += rows[r][k] * w;
    }
    float* outp = R + ((size_t)v * N_ + m0) * C_ + c;
    for (int r = 0; r < 16; ++r) outp[(size_t)r * C_] = acc[r];
}

// ---- relWT[p][c], p = i*4+j ----
__global__ void relwt_k(const float* __restrict__ T, const float* __restrict__ WT,
                        float* __restrict__ relwt) {
    int p = blockIdx.x; int i = p >> 2, j = p & 3;
    if (i == j) return;
    int c = threadIdx.x;
    float acc = 0.f;
    for (int k = 0; k < 16; ++k) acc += T[i * 16 + k] * WT[(size_t)k * C_ + c];
    for (int k = 0; k < 16; ++k) acc += T[j * 16 + k] * WT[(size_t)(16 + k) * C_ + c];
    relwt[(size_t)p * C_ + c] = acc;
}

// ---- sf8T[v][c][n] = fp8(sf[n][v][c]) ----
__global__ void sfT_k(const float* __restrict__ sf, unsigned char* __restrict__ sf8T) {
    __shared__ float Tt[64 * 65];   // [c][n]
    int n0 = blockIdx.x * 64, c0 = blockIdx.y * 64, v = blockIdx.z;
    int t = threadIdx.x;
    int nr = t >> 2, cq = (t & 3) * 16;
    const float* src = sf + ((size_t)(n0 + nr) * V_ + v) * C_ + c0 + cq;
    for (int u = 0; u < 16; ++u) Tt[(cq + u) * 65 + nr] = src[u];
    __syncthreads();
    int cr = t >> 2, nq = (t & 3) * 16;
    unsigned int wb[4];
#pragma unroll
    for (int g = 0; g < 4; ++g) {
        const float* p = Tt + cr * 65 + nq + g * 4;
        wb[g] = pk4fp8(p[0], p[1], p[2], p[3]);
    }
    unsigned char* dst = sf8T + ((size_t)v * C_ + c0 + cr) * N_ + n0 + nq;
    *(uint4*)dst = make_uint4(wb[0], wb[1], wb[2], wb[3]);
}

__global__ void zero_k(float* sq, int* cnt) {
    if (threadIdx.x < 16) { sq[threadIdx.x] = 0.f; cnt[threadIdx.x] = 0; }
}

// ---- sim GEMM (split-bf16, 3 MFMA) + exp-once stats + fp8 E/ET epilogue ----
__global__ __launch_bounds__(256) void sim_mfma_k(
    const unsigned short* __restrict__ Ahi, const unsigned short* __restrict__ Alo,
    const unsigned short* __restrict__ Bhi, const unsigned short* __restrict__ Blo,
    unsigned char* __restrict__ E8, unsigned char* __restrict__ ET8,
    float* __restrict__ rpMax, int* __restrict__ rpArg, float* __restrict__ rpSum,
    float* __restrict__ cpMax, int* __restrict__ cpArg, float* __restrict__ cpSum) {
    __shared__ unsigned char smem[36864];
    __shared__ float sRedM[256];
    __shared__ int   sRedA[256];
    __shared__ float sRedS[256];
    unsigned short* sAh = (unsigned short*)smem;          // [64][72]
    unsigned short* sAl = sAh + 64 * 72;
    unsigned short* sBh = sAl + 64 * 72;
    unsigned short* sBl = sBh + 64 * 72;
    float* S = (float*)smem;                               // [64][65] alias, holds expS

    int tid = threadIdx.x;
    int m0 = blockIdx.y * 64, n0 = blockIdx.x * 64;
    int w = tid >> 6, l = tid & 63;
    int wm = w & 1, wn = w >> 1;
    int mr = l & 15, q = l >> 4;

    f32x4 acc[2][2];
#pragma unroll
    for (int a = 0; a < 2; ++a)
#pragma unroll
        for (int b = 0; b < 2; ++b)
#pragma unroll
            for (int u = 0; u < 4; ++u) acc[a][b][u] = 0.f;

    int r = tid >> 2;
    int k8 = (tid & 3) * 8;

    for (int k0 = 0; k0 < C_; k0 += 64) {
        size_t ga = (size_t)(m0 + r) * C_ + k0 + k8;
        size_t gb = (size_t)(n0 + r) * C_ + k0 + k8;
        uint4 a0 = *(const uint4*)(Ahi + ga);
        uint4 a1 = *(const uint4*)(Ahi + ga + 32);
        uint4 a2 = *(const uint4*)(Alo + ga);
        uint4 a3 = *(const uint4*)(Alo + ga + 32);
        uint4 b0 = *(const uint4*)(Bhi + gb);
        uint4 b1 = *(const uint4*)(Bhi + gb + 32);
        uint4 b2 = *(const uint4*)(Blo + gb);
        uint4 b3 = *(const uint4*)(Blo + gb + 32);
        *(uint4*)(sAh + r * 72 + k8)      = a0;
        *(uint4*)(sAh + r * 72 + k8 + 32) = a1;
        *(uint4*)(sAl + r * 72 + k8)      = a2;
        *(uint4*)(sAl + r * 72 + k8 + 32) = a3;
        *(uint4*)(sBh + r * 72 + k8)      = b0;
        *(uint4*)(sBh + r * 72 + k8 + 32) = b1;
        *(uint4*)(sBl + r * 72 + k8)      = b2;
        *(uint4*)(sBl + r * 72 + k8 + 32) = b3;
        __syncthreads();
#pragma unroll
        for (int ks = 0; ks < 64; ks += 32) {
            bf16x8 ah[2], al[2], bh[2], bl[2];
#pragma unroll
            for (int ti = 0; ti < 2; ++ti) {
                int mrow = wm * 32 + ti * 16 + mr;
                ah[ti] = *(const bf16x8*)(sAh + mrow * 72 + ks + q * 8);
                al[ti] = *(const bf16x8*)(sAl + mrow * 72 + ks + q * 8);
            }
#pragma unroll
            for (int tj = 0; tj < 2; ++tj) {
                int nrow = wn * 32 + tj * 16 + mr;
                bh[tj] = *(const bf16x8*)(sBh + nrow * 72 + ks + q * 8);
                bl[tj] = *(const bf16x8*)(sBl + nrow * 72 + ks + q * 8);
            }
#pragma unroll
            for (int ti = 0; ti < 2; ++ti)
#pragma unroll
                for (int tj = 0; tj < 2; ++tj) {
                    acc[ti][tj] = mfma16(ah[ti], bh[tj], acc[ti][tj]);
                    acc[ti][tj] = mfma16(ah[ti], bl[tj], acc[ti][tj]);
                    acc[ti][tj] = mfma16(al[ti], bh[tj], acc[ti][tj]);
                }
        }
        __syncthreads();
    }

    // ---- epilogue: exp once into LDS (monotone -> argmax/sum equivalent) ----
#pragma unroll
    for (int ti = 0; ti < 2; ++ti)
#pragma unroll
        for (int tj = 0; tj < 2; ++tj)
#pragma unroll
            for (int rg = 0; rg < 4; ++rg)
                S[(wm * 32 + ti * 16 + q * 4 + rg) * 65 + wn * 32 + tj * 16 + mr] =
                    __expf(acc[ti][tj][rg]);
    __syncthreads();

    // row stats
    {
        int rr = tid >> 2, q4 = tid & 3;
        float mx = -1e30f; int ag = 0; float sm = 0.f;
        for (int cc = 0; cc < 16; ++cc) {
            int c = q4 * 16 + cc;
            float v = S[rr * 65 + c];
            sm += v;
            if (v > mx) { mx = v; ag = c; }
        }
        sRedM[tid] = mx; sRedA[tid] = ag; sRedS[tid] = sm;
    }
    __syncthreads();
    if (tid < 64) {
        float mx = -1e30f; int ag = 0; float sm = 0.f;
        for (int qq = 0; qq < 4; ++qq) {
            float v = sRedM[tid * 4 + qq];
            if (v > mx) { mx = v; ag = sRedA[tid * 4 + qq]; }
            sm += sRedS[tid * 4 + qq];
        }
        size_t o = (size_t)blockIdx.x * N_ + m0 + tid;
        rpMax[o] = mx; rpArg[o] = n0 + ag; rpSum[o] = sm;
    }
    __syncthreads();
    // col stats
    {
        int cc = tid >> 2, q4 = tid & 3;
        float mx = -1e30f; int ag = 0; float sm = 0.f;
        for (int rr = 0; rr < 16; ++rr) {
            int rrr = q4 * 16 + rr;
            float v = S[rrr * 65 + cc];
            sm += v;
            if (v > mx) { mx = v; ag = rrr; }
        }
        sRedM[tid] = mx; sRedA[tid] = ag; sRedS[tid] = sm;
    }
    __syncthreads();
    if (tid < 64) {
        float mx = -1e30f; int ag = 0; float sm = 0.f;
        for (int qq = 0; qq < 4; ++qq) {
            float v = sRedM[tid * 4 + qq];
            if (v > mx) { mx = v; ag = sRedA[tid * 4 + qq]; }
            sm += sRedS[tid * 4 + qq];
        }
        size_t o = (size_t)blockIdx.y * N_ + n0 + tid;
        cpMax[o] = mx; cpArg[o] = m0 + ag; cpSum[o] = sm;
    }
    // E store (fp8), row-major
    {
        int r2 = tid >> 2, cq = (tid & 3) * 16;
        unsigned int wb[4];
#pragma unroll
        for (int g = 0; g < 4; ++g) {
            const float* p = S + r2 * 65 + cq + g * 4;
            wb[g] = pk4fp8(p[0], p[1], p[2], p[3]);
        }
        *(uint4*)(E8 + (size_t)(m0 + r2) * N_ + n0 + cq) = make_uint4(wb[0], wb[1], wb[2], wb[3]);
    }
    // ET store (fp8), row-major in n
    {
        int n2 = tid >> 2, mq = (tid & 3) * 16;
        unsigned int wb[4];
#pragma unroll
        for (int g = 0; g < 4; ++g) {
            wb[g] = pk4fp8(S[(mq + g * 4 + 0) * 65 + n2], S[(mq + g * 4 + 1) * 65 + n2],
                           S[(mq + g * 4 + 2) * 65 + n2], S[(mq + g * 4 + 3) * 65 + n2]);
        }
        *(uint4*)(ET8 + (size_t)(n0 + n2) * N_ + m0 + mq) = make_uint4(wb[0], wb[1], wb[2], wb[3]);
    }
}

// ---- fused merge of row/col tile-partials; grid (64, 2) ----
__global__ __launch_bounds__(256) void merge_k(
    const float* __restrict__ rpMax, const int* __restrict__ rpArg,
    const float* __restrict__ rpSum, const float* __restrict__ cpMax,
    const int* __restrict__ cpArg, const float* __restrict__ cpSum,
    int* __restrict__ rowArg, float* __restrict__ rowSum,
    int* __restrict__ colArg, float* __restrict__ colSum) {
    int d = blockIdx.y;
    const float* pMax = d ? cpMax : rpMax;
    const int*   pArg = d ? cpArg : rpArg;
    const float* pSum = d ? cpSum : rpSum;
    int*   outArg = d ? colArg : rowArg;
    float* outSum = d ? colSum : rowSum;
    int tid = threadIdx.x;
    int li = tid & 63, g = tid >> 6;
    int m = blockIdx.x * 64 + li;
    float mx = -1e30f; int ag = 0; float sm = 0.f;
    for (int t = g * 16; t < g * 16 + 16; ++t) {
        float v = pMax[(size_t)t * N_ + m];
        if (v > mx) { mx = v; ag = pArg[(size_t)t * N_ + m]; }
        sm += pSum[(size_t)t * N_ + m];
    }
    __shared__ float sMx[256], sSm[256];
    __shared__ int sAg[256];
    sMx[g * 64 + li] = mx; sAg[g * 64 + li] = ag; sSm[g * 64 + li] = sm;
    __syncthreads();
    if (tid < 64) {
        float M = sMx[tid]; int A = sAg[tid]; float Ssum = sSm[tid];
        for (int gg = 1; gg < 4; ++gg) {
            float v = sMx[gg * 64 + tid];
            if (v > M) { M = v; A = sAg[gg * 64 + tid]; }
            Ssum += sSm[gg * 64 + tid];
        }
        outArg[m] = A; outSum[m] = Ssum;
    }
}

// ---- pass2: fp8 GEMM (32m x 64c, K=4096) + fused loss; XCD-swizzled 1-D grid ----
// 1024 blocks: xcd = lin&7; the 4 c-tiles of each (m-tile,dir) share an XCD.
__global__ __launch_bounds__(256) void p2_k(
    const unsigned char* __restrict__ E8, const unsigned char* __restrict__ ET8,
    const unsigned char* __restrict__ sf8T, int iview, int jview,
    const int* __restrict__ rowArg, const int* __restrict__ colArg,
    const float* __restrict__ rowSum, const float* __restrict__ colSum,
    const float* __restrict__ Ri, const float* __restrict__ Rj,
    const float* __restrict__ relwt, int pid0, int pid1,
    float* __restrict__ pairSq, int* __restrict__ pairCnt) {
    __shared__ unsigned char sA[32 * 144];
    __shared__ unsigned char sB[64 * 144];
    __shared__ float red[256];
    __shared__ int   mutS[32];
    __shared__ float invS[32];
    int tid = threadIdx.x;
    int lin = blockIdx.x;
    int xcd = lin & 7, slot = lin >> 3;
    int grp = xcd + 8 * (slot >> 2);   // 0..255
    int ct = slot & 3;                 // c-tile 0..3
    int mt = grp & 127, d = grp >> 7;  // m-tile 0..127, dir 0/1
    const unsigned char* A = d ? ET8 : E8;
    const unsigned char* B = sf8T + (size_t)(d ? iview : jview) * C_ * N_;
    const int* fa = d ? colArg : rowArg;
    const int* ba = d ? rowArg : colArg;
    const float* sumE = d ? colSum : rowSum;
    const float* Rr = d ? Rj : Ri;
    int pid = d ? pid1 : pid0;
    int c0 = ct * 64, m0 = mt * 32;
    int w = tid >> 6, l = tid & 63, wm = w & 1, wn = w >> 1;
    int mr = l & 15, q = l >> 4;
    if (tid < 32) {
        int y = m0 + tid;
        mutS[tid] = (ba[fa[y]] == y) ? 1 : 0;
        invS[tid] = 1.0f / sumE[y];
    }
    f32x4 acc[2];
#pragma unroll
    for (int b = 0; b < 2; ++b)
#pragma unroll
        for (int u = 0; u < 4; ++u) acc[b][u] = 0.f;

    int ra = tid >> 3, ka = (tid & 7) * 16;       // A: 32 rows x 128B, 1 uint4/thread
    int rb = tid >> 2, kb = (tid & 3) * 32;       // B: 64 rows x 128B, 2 uint4/thread
    const unsigned char* Arow = A + (size_t)(m0 + ra) * N_;
    const unsigned char* Brow = B + (size_t)(c0 + rb) * N_;
    uint4 pa  = *(const uint4*)(Arow + ka);
    uint4 pb0 = *(const uint4*)(Brow + kb);
    uint4 pb1 = *(const uint4*)(Brow + kb + 16);
    for (int k0 = 0; k0 < N_; k0 += 128) {
        *(uint4*)(sA + ra * 144 + ka)      = pa;
        *(uint4*)(sB + rb * 144 + kb)      = pb0;
        *(uint4*)(sB + rb * 144 + kb + 16) = pb1;
        __syncthreads();
        int kn = k0 + 128;
        if (kn < N_) {
            pa  = *(const uint4*)(Arow + kn + ka);
            pb0 = *(const uint4*)(Brow + kn + kb);
            pb1 = *(const uint4*)(Brow + kn + kb + 16);
        }
#pragma unroll
        for (int ksub = 0; ksub < 128; ksub += 32) {
            long af = *(const long*)(sA + (wm * 16 + mr) * 144 + ksub + q * 8);
            long b0 = *(const long*)(sB + (wn * 32 + mr) * 144 + ksub + q * 8);
            long b1 = *(const long*)(sB + (wn * 32 + 16 + mr) * 144 + ksub + q * 8);
            acc[0] = __builtin_amdgcn_mfma_f32_16x16x32_fp8_fp8(af, b0, acc[0], 0, 0, 0);
            acc[1] = __builtin_amdgcn_mfma_f32_16x16x32_fp8_fp8(af, b1, acc[1], 0, 0, 0);
        }
        __syncthreads();
    }
    const float* rw = relwt + (size_t)pid * C_;
    float local = 0.f;
#pragma unroll
    for (int tj = 0; tj < 2; ++tj) {
        int c = c0 + wn * 32 + tj * 16 + mr;
        float rwc = rw[c];
#pragma unroll
        for (int rg = 0; rg < 4; ++rg) {
            int ml = wm * 16 + q * 4 + rg;
            if (mutS[ml]) {
                int m = m0 + ml;
                float soft = acc[tj][rg] * invS[ml];
                float dv = Rr[(size_t)m * C_ + c] + rwc - soft;
                local += dv * dv;
            }
        }
    }
    red[tid] = local;
    __syncthreads();
    for (int s = 128; s > 0; s >>= 1) {
        if (tid < s) red[tid] += red[tid + s];
        __syncthreads();
    }
    if (tid == 0) {
        atomicAdd(pairSq + pid, red[0]);
        if (ct == 0) {
            int cnt = 0;
            for (int u = 0; u < 32; ++u) cnt += mutS[u];
            atomicAdd(pairCnt + pid, cnt);
        }
    }
}

// ---- final scalar combine ----
__global__ void final_k(const float* __restrict__ sq, const int* __restrict__ cnt,
                        float* __restrict__ out) {
    if (threadIdx.x == 0 && blockIdx.x == 0) {
        float loss = 0.f, count = 0.f;
        for (int p = 0; p < 16; ++p) {
            int i = p >> 2, j = p & 3;
            if (i == j) continue;
            float ns = (float)cnt[p];
            if (ns > 0.f) { loss += sq[p] / fmaxf(ns * (float)C_, 1.0f); count += 1.f; }
        }
        out[0] = (count > 0.f) ? loss / count : 0.f;
    }
}

extern "C" void kernel_launch(void* const* d_in, const int* in_sizes, int n_in,
                              void* d_out, int out_size, void* d_ws, size_t ws_size,
                              hipStream_t stream) {
    const float* desc = (const float*)d_in[0];
    const float* sf   = (const float*)d_in[1];
    const float* T    = (const float*)d_in[2];
    const float* Wrec = (const float*)d_in[3];
    const float* WT   = (const float*)d_in[4];
    float* out = (float*)d_out;
    char* ws = (char*)d_ws;

    float*          dn    = (float*)(ws + OFF_DN);
    float*          R     = (float*)(ws + OFF_R);
    unsigned short* dnh   = (unsigned short*)(ws + OFF_DNHI);
    unsigned short* dnl   = (unsigned short*)(ws + OFF_DNLO);
    unsigned char*  sf8T  = (unsigned char*)(ws + OFF_SFT);
    unsigned char*  E8    = (unsigned char*)(ws + OFF_E);
    unsigned char*  ET8   = (unsigned char*)(ws + OFF_ET);
    float* rpMax = (float*)(ws + OFF_RPMAX);
    int*   rpArg = (int*)(ws + OFF_RPARG);
    float* rpSum = (float*)(ws + OFF_RPSUM);
    float* cpMax = (float*)(ws + OFF_CPMAX);
    int*   cpArg = (int*)(ws + OFF_CPARG);
    float* cpSum = (float*)(ws + OFF_CPSUM);
    int*   rowArg = (int*)(ws + OFF_RARG);
    float* rowSum = (float*)(ws + OFF_RSUM);
    int*   colArg = (int*)(ws + OFF_CARG);
    float* colSum = (float*)(ws + OFF_CSUM);
    float* relwt = (float*)(ws + OFF_RELWT);
    float* pairSq = (float*)(ws + OFF_SQ);
    int*   pairCnt = (int*)(ws + OFF_CNT);

    normalize_k<<<N_ * V_, 256, 0, stream>>>(desc, dn, dnh, dnl);
    rmatmul_k<<<dim3(N_ / 16, V_), 256, 0, stream>>>(dn, Wrec, R);
    sfT_k<<<dim3(64, 4, 4), 256, 0, stream>>>(sf, sf8T);
    relwt_k<<<16, 256, 0, stream>>>(T, WT, relwt);
    zero_k<<<1, 64, 0, stream>>>(pairSq, pairCnt);

    for (int i = 0; i < V_; ++i) {
        for (int j = i + 1; j < V_; ++j) {
            const unsigned short* Ahi = dnh + (size_t)i * N_ * C_;
            const unsigned short* Alo = dnl + (size_t)i * N_ * C_;
            const unsigned short* Bhi = dnh + (size_t)j * N_ * C_;
            const unsigned short* Blo = dnl + (size_t)j * N_ * C_;
            sim_mfma_k<<<dim3(64, 64), 256, 0, stream>>>(
                Ahi, Alo, Bhi, Blo, E8, ET8, rpMax, rpArg, rpSum, cpMax, cpArg, cpSum);
            merge_k<<<dim3(64, 2), 256, 0, stream>>>(
                rpMax, rpArg, rpSum, cpMax, cpArg, cpSum, rowArg, rowSum, colArg, colSum);
            int pid0 = i * 4 + j, pid1 = j * 4 + i;
            p2_k<<<1024, 256, 0, stream>>>(
                E8, ET8, sf8T, i, j, rowArg, colArg, rowSum, colSum,
                R + (size_t)i * N_ * C_, R + (size_t)j * N_ * C_,
                relwt, pid0, pid1, pairSq, pairCnt);
        }
    }
    final_k<<<1, 64, 0, stream>>>(pairSq, pairCnt, out);
}